// Round 1
// baseline (2290.018 us; speedup 1.0000x reference)
//
#include <hip/hip_runtime.h>
#include <cstdint>

// ---------------- degree / dinv ----------------
__global__ __launch_bounds__(256) void deg_kernel(const int* __restrict__ dst,
                                                  int* __restrict__ deg, int nE) {
  int e = blockIdx.x * 256 + threadIdx.x;
  if (e < nE) atomicAdd(&deg[dst[e]], 1);
}

__global__ __launch_bounds__(256) void dinv_kernel(const int* __restrict__ deg,
                                                   float* __restrict__ dinv, int n) {
  int i = blockIdx.x * 256 + threadIdx.x;
  if (i < n) dinv[i] = rsqrtf((float)deg[i] + 1.0f);
}

// ---------------- exclusive scan (3 kernels) ----------------
__global__ __launch_bounds__(256) void scan1_kernel(const int* __restrict__ deg,
                                                    int* __restrict__ rp,
                                                    int* __restrict__ part, int n) {
  __shared__ int sh[256];
  int b = blockIdx.x, t = threadIdx.x;
  int base = b * 1024 + t * 4;
  int v0 = (base + 0 < n) ? deg[base + 0] : 0;
  int v1 = (base + 1 < n) ? deg[base + 1] : 0;
  int v2 = (base + 2 < n) ? deg[base + 2] : 0;
  int v3 = (base + 3 < n) ? deg[base + 3] : 0;
  int ts = v0 + v1 + v2 + v3;
  sh[t] = ts;
  __syncthreads();
  for (int off = 1; off < 256; off <<= 1) {
    int x = (t >= off) ? sh[t - off] : 0;
    __syncthreads();
    sh[t] += x;
    __syncthreads();
  }
  int excl = sh[t] - ts;
  if (t == 255) part[b] = sh[255];
  if (base + 0 < n) rp[base + 0] = excl;
  if (base + 1 < n) rp[base + 1] = excl + v0;
  if (base + 2 < n) rp[base + 2] = excl + v0 + v1;
  if (base + 3 < n) rp[base + 3] = excl + v0 + v1 + v2;
}

__global__ void scan2_kernel(int* part, int* rp, int nb, int n) {
  if (blockIdx.x == 0 && threadIdx.x == 0) {
    int run = 0;
    for (int i = 0; i < nb; ++i) { int v = part[i]; part[i] = run; run += v; }
    rp[n] = run;
  }
}

__global__ __launch_bounds__(256) void scan3_kernel(int* __restrict__ rp,
                                                    const int* __restrict__ part,
                                                    int* __restrict__ cursor, int n) {
  int i = blockIdx.x * 256 + threadIdx.x;
  if (i < n) {
    int v = rp[i] + part[i >> 10];
    rp[i] = v;
    cursor[i] = v;
  }
}

// ---------------- CSR placement ----------------
__global__ __launch_bounds__(256) void place_kernel(const int* __restrict__ src,
                                                    const int* __restrict__ dst,
                                                    int* __restrict__ cursor,
                                                    int* __restrict__ ssort, int nE) {
  int e = blockIdx.x * 256 + threadIdx.x;
  if (e < nE) {
    int d = dst[e];
    int pos = atomicAdd(&cursor[d], 1);
    ssort[pos] = src[e];
  }
}

// ---------------- dense GEMM: out[N,128] = A[N,128] @ W[128,128] ----------------
__global__ __launch_bounds__(256) void gemm128_kernel(const float* __restrict__ A,
                                                      const float* __restrict__ W,
                                                      float* __restrict__ out, int nrows) {
  extern __shared__ float lds[];
  float* Ws = lds;             // 128*128 floats
  float* xs = lds + 128 * 128; // 16*128 floats
  const int t = threadIdx.x;
  for (int i = t; i < (128 * 128) / 4; i += 256)
    reinterpret_cast<float4*>(Ws)[i] = reinterpret_cast<const float4*>(W)[i];
  const int wave = t >> 6, lane = t & 63;
  for (int rb = blockIdx.x * 16; rb < nrows; rb += gridDim.x * 16) {
    int nr = min(16, nrows - rb);
    __syncthreads();
    for (int i = t; i < nr * 32; i += 256)
      reinterpret_cast<float4*>(xs)[i] =
          reinterpret_cast<const float4*>(A + (size_t)rb * 128)[i];
    __syncthreads();
    float acc[4][2] = {{0.f, 0.f}, {0.f, 0.f}, {0.f, 0.f}, {0.f, 0.f}};
    const float* xw = xs + wave * 4 * 128;
#pragma unroll 4
    for (int k = 0; k < 128; ++k) {
      float w0 = Ws[k * 128 + lane];
      float w1 = Ws[k * 128 + 64 + lane];
#pragma unroll
      for (int r = 0; r < 4; ++r) {
        float a = xw[r * 128 + k];
        acc[r][0] = fmaf(a, w0, acc[r][0]);
        acc[r][1] = fmaf(a, w1, acc[r][1]);
      }
    }
#pragma unroll
    for (int r = 0; r < 4; ++r) {
      int row = rb + wave * 4 + r;
      if (row < nrows) {
        out[(size_t)row * 128 + lane] = acc[r][0];
        out[(size_t)row * 128 + 64 + lane] = acc[r][1];
      }
    }
  }
}

// ---------------- SpMM + self-loop + bias, with BN stats ----------------
__global__ __launch_bounds__(256) void spmm_kernel(const float* __restrict__ hlin,
                                                   const float* __restrict__ dinv,
                                                   const int* __restrict__ rp,
                                                   const int* __restrict__ srcs,
                                                   const float* __restrict__ bias,
                                                   float* __restrict__ outp,
                                                   float* __restrict__ bnsum,
                                                   float* __restrict__ bnsq, int nN) {
  const int lane = threadIdx.x & 63;
  const int wid = (blockIdx.x * blockDim.x + threadIdx.x) >> 6;
  const int nw = (gridDim.x * blockDim.x) >> 6;
  float b0 = bias[lane], b1 = bias[64 + lane];
  float s0 = 0.f, s1 = 0.f, q0 = 0.f, q1 = 0.f;
  for (int n = wid; n < nN; n += nw) {
    int beg = rp[n], end = rp[n + 1];
    float dn = dinv[n];
    float a0 = 0.f, a1 = 0.f;
    for (int j = beg; j < end; ++j) {
      int s = srcs[j];
      float wgt = dinv[s] * dn;
      const float* hp = hlin + (size_t)s * 128;
      a0 = fmaf(wgt, hp[lane], a0);
      a1 = fmaf(wgt, hp[64 + lane], a1);
    }
    float sw = dn * dn;
    const float* hn = hlin + (size_t)n * 128;
    float o0 = fmaf(hn[lane], sw, a0) + b0;
    float o1 = fmaf(hn[64 + lane], sw, a1) + b1;
    float* op = outp + (size_t)n * 128;
    op[lane] = o0;
    op[64 + lane] = o1;
    s0 += o0; s1 += o1;
    q0 = fmaf(o0, o0, q0); q1 = fmaf(o1, o1, q1);
  }
  atomicAdd(&bnsum[lane], s0);
  atomicAdd(&bnsum[64 + lane], s1);
  atomicAdd(&bnsq[lane], q0);
  atomicAdd(&bnsq[64 + lane], q1);
}

// ---------------- BN finalize + apply ----------------
__global__ void bnfin_kernel(const float* __restrict__ sum, const float* __restrict__ sq,
                             const float* __restrict__ gamma, const float* __restrict__ beta,
                             float* __restrict__ scale, float* __restrict__ shift,
                             float invN) {
  int c = threadIdx.x;
  float mu = sum[c] * invN;
  float var = sq[c] * invN - mu * mu;
  float sc = gamma[c] * rsqrtf(var + 1e-5f);
  scale[c] = sc;
  shift[c] = beta[c] - mu * sc;
}

__global__ __launch_bounds__(256) void bnapply_kernel(const float* __restrict__ in,
                                                      const float* __restrict__ scale,
                                                      const float* __restrict__ shift,
                                                      float* __restrict__ out, int total4) {
  int i = blockIdx.x * blockDim.x + threadIdx.x;
  int stride = gridDim.x * blockDim.x;
  for (; i < total4; i += stride) {
    float4 v = reinterpret_cast<const float4*>(in)[i];
    int c = (i * 4) & 127;
    float4 o;
    o.x = fmaxf(fmaf(v.x, scale[c + 0], shift[c + 0]), 0.f);
    o.y = fmaxf(fmaf(v.y, scale[c + 1], shift[c + 1]), 0.f);
    o.z = fmaxf(fmaf(v.z, scale[c + 2], shift[c + 2]), 0.f);
    o.w = fmaxf(fmaf(v.w, scale[c + 3], shift[c + 3]), 0.f);
    reinterpret_cast<float4*>(out)[i] = o;
  }
}

// ---------------- graph mean pool (batch_idx sorted -> run-length) ----------------
__global__ __launch_bounds__(256) void pool_kernel(const float* __restrict__ h,
                                                   const int* __restrict__ batch,
                                                   float* __restrict__ gsum,
                                                   float* __restrict__ gcnt,
                                                   int nN, int chunk) {
  const int lane = threadIdx.x & 63;
  const int wid = (blockIdx.x * blockDim.x + threadIdx.x) >> 6;
  int beg = wid * chunk;
  if (beg >= nN) return;
  int end = min(nN, beg + chunk);
  int cur = -1;
  float a0 = 0.f, a1 = 0.f, cnt = 0.f;
  for (int n = beg; n < end; ++n) {
    int g = batch[n];
    if (g != cur) {
      if (cur >= 0) {
        atomicAdd(&gsum[cur * 128 + lane], a0);
        atomicAdd(&gsum[cur * 128 + 64 + lane], a1);
        if (lane == 0) atomicAdd(&gcnt[cur], cnt);
      }
      cur = g; a0 = 0.f; a1 = 0.f; cnt = 0.f;
    }
    const float* hp = h + (size_t)n * 128;
    a0 += hp[lane];
    a1 += hp[64 + lane];
    cnt += 1.f;
  }
  if (cur >= 0) {
    atomicAdd(&gsum[cur * 128 + lane], a0);
    atomicAdd(&gsum[cur * 128 + 64 + lane], a1);
    if (lane == 0) atomicAdd(&gcnt[cur], cnt);
  }
}

// ---------------- edge MLP layer1 + per-graph sum (LDS accumulate) ----------------
__global__ __launch_bounds__(512) void edge_kernel(const float* __restrict__ ea,
                                                   const int* __restrict__ src,
                                                   const int* __restrict__ batch,
                                                   const float* __restrict__ We1,
                                                   const float* __restrict__ be1,
                                                   float* __restrict__ esum,
                                                   float* __restrict__ ecnt, int nE) {
  extern __shared__ float es[]; // 256*128 + 256 floats
  float* cs = es + 256 * 128;
  const int t = threadIdx.x;
  for (int i = t; i < 256 * 128 + 256; i += 512) es[i] = 0.f;
  const int lane = t & 63;
  float w0[16], w1[16];
#pragma unroll
  for (int k = 0; k < 16; ++k) {
    w0[k] = We1[k * 128 + lane];
    w1[k] = We1[k * 128 + 64 + lane];
  }
  float b0 = be1[lane], b1 = be1[64 + lane];
  __syncthreads();
  const int wid = (blockIdx.x * 512 + t) >> 6;
  const int nw = (gridDim.x * 512) >> 6;
  for (int e = wid; e < nE; e += nw) {
    int s = src[e];
    int g = batch[s];
    float av[16];
    {
      const float4* eap = reinterpret_cast<const float4*>(ea + (size_t)e * 16);
      float4 t0 = eap[0], t1 = eap[1], t2 = eap[2], t3 = eap[3];
      av[0] = t0.x; av[1] = t0.y; av[2] = t0.z; av[3] = t0.w;
      av[4] = t1.x; av[5] = t1.y; av[6] = t1.z; av[7] = t1.w;
      av[8] = t2.x; av[9] = t2.y; av[10] = t2.z; av[11] = t2.w;
      av[12] = t3.x; av[13] = t3.y; av[14] = t3.z; av[15] = t3.w;
    }
    float u0 = b0, u1 = b1;
#pragma unroll
    for (int k = 0; k < 16; ++k) {
      u0 = fmaf(av[k], w0[k], u0);
      u1 = fmaf(av[k], w1[k], u1);
    }
    u0 = fmaxf(u0, 0.f);
    u1 = fmaxf(u1, 0.f);
    atomicAdd(&es[g * 128 + lane], u0);
    atomicAdd(&es[g * 128 + 64 + lane], u1);
    if (lane == 0) atomicAdd(&cs[g], 1.f);
  }
  __syncthreads();
  for (int i = t; i < 256 * 128; i += 512) atomicAdd(&esum[i], es[i]);
  for (int i = t; i < 256; i += 512) atomicAdd(&ecnt[i], cs[i]);
}

// ---------------- final: graph_repr + edge_repr ----------------
__global__ __launch_bounds__(128) void final_kernel(const float* __restrict__ gsum,
                                                    const float* __restrict__ gcnt,
                                                    const float* __restrict__ esum,
                                                    const float* __restrict__ ecnt,
                                                    const float* __restrict__ We2,
                                                    const float* __restrict__ be2,
                                                    float* __restrict__ out) {
  __shared__ float row[128];
  int g = blockIdx.x, c = threadIdx.x;
  row[c] = esum[g * 128 + c];
  __syncthreads();
  float acc = 0.f;
#pragma unroll 4
  for (int k = 0; k < 128; ++k) acc = fmaf(row[k], We2[k * 128 + c], acc);
  float ce = ecnt[g];
  float er = (ce > 0.f) ? (acc / ce + be2[c]) : 0.f;
  float cn = gcnt[g];
  float gr = gsum[g * 128 + c] / fmaxf(cn, 1.f);
  out[g * 128 + c] = gr + er;
}

extern "C" void kernel_launch(void* const* d_in, const int* in_sizes, int n_in,
                              void* d_out, int out_size, void* d_ws, size_t ws_size,
                              hipStream_t stream) {
  const float* x    = (const float*)d_in[0];
  const int*   ei   = (const int*)d_in[1];
  const float* ea   = (const float*)d_in[2];
  const int*   bidx = (const int*)d_in[3];
  const float* Wg1  = (const float*)d_in[4];
  const float* bg1  = (const float*)d_in[5];
  const float* gm1  = (const float*)d_in[6];
  const float* bt1  = (const float*)d_in[7];
  const float* Wg2  = (const float*)d_in[8];
  const float* bg2  = (const float*)d_in[9];
  const float* gm2  = (const float*)d_in[10];
  const float* bt2  = (const float*)d_in[11];
  const float* We1  = (const float*)d_in[12];
  const float* be1  = (const float*)d_in[13];
  const float* We2  = (const float*)d_in[14];
  const float* be2  = (const float*)d_in[15];
  float* out = (float*)d_out;

  const int N = in_sizes[3];
  const int E = in_sizes[1] / 2;
  const int G = out_size / 128;
  const int* srcp = ei;
  const int* dstp = ei + E;

  char* w = (char*)d_ws;
  auto alloc = [&](size_t b) {
    char* p = w;
    w += (b + 15) & ~(size_t)15;
    return p;
  };
  float* bufA   = (float*)alloc((size_t)N * 128 * 4);
  float* bufB   = (float*)alloc((size_t)N * 128 * 4);
  int*   ssort  = (int*)alloc((size_t)E * 4);
  int*   rp     = (int*)alloc((size_t)(N + 1) * 4);
  int*   cursor = (int*)alloc((size_t)N * 4);
  float* dinv   = (float*)alloc((size_t)N * 4);
  char* zbase = w;
  int*   deg  = (int*)alloc((size_t)N * 4);
  float* bs1  = (float*)alloc(512);
  float* bq1  = (float*)alloc(512);
  float* bs2  = (float*)alloc(512);
  float* bq2  = (float*)alloc(512);
  float* gsum = (float*)alloc((size_t)G * 128 * 4);
  float* gcnt = (float*)alloc((size_t)G * 4);
  float* esum = (float*)alloc((size_t)G * 128 * 4);
  float* ecnt = (float*)alloc((size_t)G * 4);
  int*   part = (int*)alloc(4096);
  size_t zbytes = (size_t)(w - zbase);
  float* sc1 = (float*)alloc(512);
  float* sh1 = (float*)alloc(512);
  float* sc2 = (float*)alloc(512);
  float* sh2 = (float*)alloc(512);

  hipMemsetAsync(zbase, 0, zbytes, stream);

  (void)hipFuncSetAttribute((const void*)gemm128_kernel,
                            hipFuncAttributeMaxDynamicSharedMemorySize, 73728);
  (void)hipFuncSetAttribute((const void*)edge_kernel,
                            hipFuncAttributeMaxDynamicSharedMemorySize, 132096);

  deg_kernel<<<(E + 255) / 256, 256, 0, stream>>>(dstp, deg, E);
  dinv_kernel<<<(N + 255) / 256, 256, 0, stream>>>(deg, dinv, N);
  int nb = (N + 1023) / 1024;
  scan1_kernel<<<nb, 256, 0, stream>>>(deg, rp, part, N);
  scan2_kernel<<<1, 1, 0, stream>>>(part, rp, nb, N);
  scan3_kernel<<<(N + 255) / 256, 256, 0, stream>>>(rp, part, cursor, N);
  place_kernel<<<(E + 255) / 256, 256, 0, stream>>>(srcp, dstp, cursor, ssort, E);

  // layer 1
  gemm128_kernel<<<512, 256, 73728, stream>>>(x, Wg1, bufA, N);
  spmm_kernel<<<2048, 256, 0, stream>>>(bufA, dinv, rp, ssort, bg1, bufB, bs1, bq1, N);
  bnfin_kernel<<<1, 128, 0, stream>>>(bs1, bq1, gm1, bt1, sc1, sh1, 1.0f / (float)N);
  bnapply_kernel<<<4096, 256, 0, stream>>>(bufB, sc1, sh1, bufA, N * 32);

  // layer 2
  gemm128_kernel<<<512, 256, 73728, stream>>>(bufA, Wg2, bufB, N);
  spmm_kernel<<<2048, 256, 0, stream>>>(bufB, dinv, rp, ssort, bg2, bufA, bs2, bq2, N);
  bnfin_kernel<<<1, 128, 0, stream>>>(bs2, bq2, gm2, bt2, sc2, sh2, 1.0f / (float)N);
  bnapply_kernel<<<4096, 256, 0, stream>>>(bufA, sc2, sh2, bufB, N * 32);

  // pooling + edge path + output
  int nwp = (2048 * 256) / 64;
  int chunk = (N + nwp - 1) / nwp;
  pool_kernel<<<2048, 256, 0, stream>>>(bufB, bidx, gsum, gcnt, N, chunk);
  edge_kernel<<<256, 512, 132096, stream>>>(ea, srcp, bidx, We1, be1, esum, ecnt, E);
  final_kernel<<<G, 128, 0, stream>>>(gsum, gcnt, esum, ecnt, We2, be2, out);
}

// Round 2
// 1708.570 us; speedup vs baseline: 1.3403x; 1.3403x over previous
//
#include <hip/hip_runtime.h>
#include <cstdint>

// ---------------- degree histograms (dst for GCN norm, src for edge sort) ----------------
__global__ __launch_bounds__(256) void pre_kernel(const int* __restrict__ src,
                                                  const int* __restrict__ dst,
                                                  int* __restrict__ deg,
                                                  int* __restrict__ deg2, int nE) {
  int e = blockIdx.x * 256 + threadIdx.x;
  if (e < nE) {
    atomicAdd(&deg[dst[e]], 1);
    atomicAdd(&deg2[src[e]], 1);
  }
}

__global__ __launch_bounds__(256) void dinv_kernel(const int* __restrict__ deg,
                                                   float* __restrict__ dinv, int n) {
  int i = blockIdx.x * 256 + threadIdx.x;
  if (i < n) dinv[i] = rsqrtf((float)deg[i] + 1.0f);
}

// ---------------- exclusive scan (3 kernels) ----------------
__global__ __launch_bounds__(256) void scan1_kernel(const int* __restrict__ deg,
                                                    int* __restrict__ rp,
                                                    int* __restrict__ part, int n) {
  __shared__ int sh[256];
  int b = blockIdx.x, t = threadIdx.x;
  int base = b * 1024 + t * 4;
  int v0 = (base + 0 < n) ? deg[base + 0] : 0;
  int v1 = (base + 1 < n) ? deg[base + 1] : 0;
  int v2 = (base + 2 < n) ? deg[base + 2] : 0;
  int v3 = (base + 3 < n) ? deg[base + 3] : 0;
  int ts = v0 + v1 + v2 + v3;
  sh[t] = ts;
  __syncthreads();
  for (int off = 1; off < 256; off <<= 1) {
    int x = (t >= off) ? sh[t - off] : 0;
    __syncthreads();
    sh[t] += x;
    __syncthreads();
  }
  int excl = sh[t] - ts;
  if (t == 255) part[b] = sh[255];
  if (base + 0 < n) rp[base + 0] = excl;
  if (base + 1 < n) rp[base + 1] = excl + v0;
  if (base + 2 < n) rp[base + 2] = excl + v0 + v1;
  if (base + 3 < n) rp[base + 3] = excl + v0 + v1 + v2;
}

__global__ void scan2_kernel(int* part, int* rp, int nb, int n) {
  if (blockIdx.x == 0 && threadIdx.x == 0) {
    int run = 0;
    for (int i = 0; i < nb; ++i) { int v = part[i]; part[i] = run; run += v; }
    rp[n] = run;
  }
}

__global__ __launch_bounds__(256) void scan3_kernel(int* __restrict__ rp,
                                                    const int* __restrict__ part,
                                                    int* __restrict__ cursor, int n) {
  int i = blockIdx.x * 256 + threadIdx.x;
  if (i < n) {
    int v = rp[i] + part[i >> 10];
    rp[i] = v;
    cursor[i] = v;
  }
}

// ---------------- CSR placement: dst-CSR (srcs per node) + src-ordered edge list ----------------
// src-ordered => graph-ordered, since batch_idx is sorted by node id.
// pack (graph<<21 | edge_id): E = 1.6M < 2^21, G = 256 -> fits u32.
__global__ __launch_bounds__(256) void place_kernel(const int* __restrict__ src,
                                                    const int* __restrict__ dst,
                                                    const int* __restrict__ batch,
                                                    int* __restrict__ cursor,
                                                    int* __restrict__ cursor2,
                                                    int* __restrict__ ssort,
                                                    unsigned int* __restrict__ epk, int nE) {
  int e = blockIdx.x * 256 + threadIdx.x;
  if (e < nE) {
    int s = src[e];
    int d = dst[e];
    int p1 = atomicAdd(&cursor[d], 1);
    ssort[p1] = s;
    int g = batch[s];
    int p2 = atomicAdd(&cursor2[s], 1);
    epk[p2] = ((unsigned int)g << 21) | (unsigned int)e;
  }
}

// ---------------- dense GEMM: out[N,128] = A[N,128] @ W[128,128] ----------------
__global__ __launch_bounds__(256) void gemm128_kernel(const float* __restrict__ A,
                                                      const float* __restrict__ W,
                                                      float* __restrict__ out, int nrows) {
  extern __shared__ float lds[];
  float* Ws = lds;             // 128*128 floats
  float* xs = lds + 128 * 128; // 16*128 floats
  const int t = threadIdx.x;
  for (int i = t; i < (128 * 128) / 4; i += 256)
    reinterpret_cast<float4*>(Ws)[i] = reinterpret_cast<const float4*>(W)[i];
  const int wave = t >> 6, lane = t & 63;
  for (int rb = blockIdx.x * 16; rb < nrows; rb += gridDim.x * 16) {
    int nr = min(16, nrows - rb);
    __syncthreads();
    for (int i = t; i < nr * 32; i += 256)
      reinterpret_cast<float4*>(xs)[i] =
          reinterpret_cast<const float4*>(A + (size_t)rb * 128)[i];
    __syncthreads();
    float acc[4][2] = {{0.f, 0.f}, {0.f, 0.f}, {0.f, 0.f}, {0.f, 0.f}};
    const float* xw = xs + wave * 4 * 128;
#pragma unroll 4
    for (int k = 0; k < 128; ++k) {
      float w0 = Ws[k * 128 + lane];
      float w1 = Ws[k * 128 + 64 + lane];
#pragma unroll
      for (int r = 0; r < 4; ++r) {
        float a = xw[r * 128 + k];
        acc[r][0] = fmaf(a, w0, acc[r][0]);
        acc[r][1] = fmaf(a, w1, acc[r][1]);
      }
    }
#pragma unroll
    for (int r = 0; r < 4; ++r) {
      int row = rb + wave * 4 + r;
      if (row < nrows) {
        out[(size_t)row * 128 + lane] = acc[r][0];
        out[(size_t)row * 128 + 64 + lane] = acc[r][1];
      }
    }
  }
}

// ---------------- SpMM + self-loop + bias, with BN stats ----------------
__global__ __launch_bounds__(256) void spmm_kernel(const float* __restrict__ hlin,
                                                   const float* __restrict__ dinv,
                                                   const int* __restrict__ rp,
                                                   const int* __restrict__ srcs,
                                                   const float* __restrict__ bias,
                                                   float* __restrict__ outp,
                                                   float* __restrict__ bnsum,
                                                   float* __restrict__ bnsq, int nN) {
  const int lane = threadIdx.x & 63;
  const int wid = (blockIdx.x * blockDim.x + threadIdx.x) >> 6;
  const int nw = (gridDim.x * blockDim.x) >> 6;
  float b0 = bias[lane], b1 = bias[64 + lane];
  float s0 = 0.f, s1 = 0.f, q0 = 0.f, q1 = 0.f;
  for (int n = wid; n < nN; n += nw) {
    int beg = rp[n], end = rp[n + 1];
    float dn = dinv[n];
    float a0 = 0.f, a1 = 0.f;
    for (int j = beg; j < end; ++j) {
      int s = srcs[j];
      float wgt = dinv[s] * dn;
      const float* hp = hlin + (size_t)s * 128;
      a0 = fmaf(wgt, hp[lane], a0);
      a1 = fmaf(wgt, hp[64 + lane], a1);
    }
    float sw = dn * dn;
    const float* hn = hlin + (size_t)n * 128;
    float o0 = fmaf(hn[lane], sw, a0) + b0;
    float o1 = fmaf(hn[64 + lane], sw, a1) + b1;
    float* op = outp + (size_t)n * 128;
    op[lane] = o0;
    op[64 + lane] = o1;
    s0 += o0; s1 += o1;
    q0 = fmaf(o0, o0, q0); q1 = fmaf(o1, o1, q1);
  }
  atomicAdd(&bnsum[lane], s0);
  atomicAdd(&bnsum[64 + lane], s1);
  atomicAdd(&bnsq[lane], q0);
  atomicAdd(&bnsq[64 + lane], q1);
}

// ---------------- BN finalize + apply ----------------
__global__ void bnfin_kernel(const float* __restrict__ sum, const float* __restrict__ sq,
                             const float* __restrict__ gamma, const float* __restrict__ beta,
                             float* __restrict__ scale, float* __restrict__ shift,
                             float invN) {
  int c = threadIdx.x;
  float mu = sum[c] * invN;
  float var = sq[c] * invN - mu * mu;
  float sc = gamma[c] * rsqrtf(var + 1e-5f);
  scale[c] = sc;
  shift[c] = beta[c] - mu * sc;
}

__global__ __launch_bounds__(256) void bnapply_kernel(const float* __restrict__ in,
                                                      const float* __restrict__ scale,
                                                      const float* __restrict__ shift,
                                                      float* __restrict__ out, int total4) {
  int i = blockIdx.x * blockDim.x + threadIdx.x;
  int stride = gridDim.x * blockDim.x;
  for (; i < total4; i += stride) {
    float4 v = reinterpret_cast<const float4*>(in)[i];
    int c = (i * 4) & 127;
    float4 o;
    o.x = fmaxf(fmaf(v.x, scale[c + 0], shift[c + 0]), 0.f);
    o.y = fmaxf(fmaf(v.y, scale[c + 1], shift[c + 1]), 0.f);
    o.z = fmaxf(fmaf(v.z, scale[c + 2], shift[c + 2]), 0.f);
    o.w = fmaxf(fmaf(v.w, scale[c + 3], shift[c + 3]), 0.f);
    reinterpret_cast<float4*>(out)[i] = o;
  }
}

// ---------------- graph mean pool (batch_idx sorted -> run-length) ----------------
__global__ __launch_bounds__(256) void pool_kernel(const float* __restrict__ h,
                                                   const int* __restrict__ batch,
                                                   float* __restrict__ gsum,
                                                   float* __restrict__ gcnt,
                                                   int nN, int chunk) {
  const int lane = threadIdx.x & 63;
  const int wid = (blockIdx.x * blockDim.x + threadIdx.x) >> 6;
  int beg = wid * chunk;
  if (beg >= nN) return;
  int end = min(nN, beg + chunk);
  int cur = -1;
  float a0 = 0.f, a1 = 0.f, cnt = 0.f;
  for (int n = beg; n < end; ++n) {
    int g = batch[n];
    if (g != cur) {
      if (cur >= 0) {
        atomicAdd(&gsum[cur * 128 + lane], a0);
        atomicAdd(&gsum[cur * 128 + 64 + lane], a1);
        if (lane == 0) atomicAdd(&gcnt[cur], cnt);
      }
      cur = g; a0 = 0.f; a1 = 0.f; cnt = 0.f;
    }
    const float* hp = h + (size_t)n * 128;
    a0 += hp[lane];
    a1 += hp[64 + lane];
    cnt += 1.f;
  }
  if (cur >= 0) {
    atomicAdd(&gsum[cur * 128 + lane], a0);
    atomicAdd(&gsum[cur * 128 + 64 + lane], a1);
    if (lane == 0) atomicAdd(&gcnt[cur], cnt);
  }
}

// ---------------- edge MLP layer1 + per-graph sum (graph-sorted, run-length regs) ----------------
__global__ __launch_bounds__(256) void edge2_kernel(const float* __restrict__ ea,
                                                    const unsigned int* __restrict__ epk,
                                                    const float* __restrict__ We1,
                                                    const float* __restrict__ be1,
                                                    float* __restrict__ esum,
                                                    float* __restrict__ ecnt,
                                                    int nE, int chunk) {
  const int lane = threadIdx.x & 63;
  const int wid = (blockIdx.x * blockDim.x + threadIdx.x) >> 6;
  int beg = wid * chunk;
  if (beg >= nE) return;
  int end = min(nE, beg + chunk);
  float w0[16], w1[16];
#pragma unroll
  for (int k = 0; k < 16; ++k) {
    w0[k] = We1[k * 128 + lane];
    w1[k] = We1[k * 128 + 64 + lane];
  }
  float b0 = be1[lane], b1 = be1[64 + lane];
  int cur = -1;
  float a0 = 0.f, a1 = 0.f, cnt = 0.f;
  for (int j = beg; j < end; ++j) {
    unsigned int pk = epk[j];
    int g = (int)(pk >> 21);
    int e = (int)(pk & 0x1FFFFFu);
    if (g != cur) {
      if (cur >= 0) {
        atomicAdd(&esum[cur * 128 + lane], a0);
        atomicAdd(&esum[cur * 128 + 64 + lane], a1);
        if (lane == 0) atomicAdd(&ecnt[cur], cnt);
      }
      cur = g; a0 = 0.f; a1 = 0.f; cnt = 0.f;
    }
    const float4* eap = reinterpret_cast<const float4*>(ea + (size_t)e * 16);
    float4 t0 = eap[0], t1 = eap[1], t2 = eap[2], t3 = eap[3];
    float u0 = b0, u1 = b1;
    u0 = fmaf(t0.x, w0[0], u0);  u1 = fmaf(t0.x, w1[0], u1);
    u0 = fmaf(t0.y, w0[1], u0);  u1 = fmaf(t0.y, w1[1], u1);
    u0 = fmaf(t0.z, w0[2], u0);  u1 = fmaf(t0.z, w1[2], u1);
    u0 = fmaf(t0.w, w0[3], u0);  u1 = fmaf(t0.w, w1[3], u1);
    u0 = fmaf(t1.x, w0[4], u0);  u1 = fmaf(t1.x, w1[4], u1);
    u0 = fmaf(t1.y, w0[5], u0);  u1 = fmaf(t1.y, w1[5], u1);
    u0 = fmaf(t1.z, w0[6], u0);  u1 = fmaf(t1.z, w1[6], u1);
    u0 = fmaf(t1.w, w0[7], u0);  u1 = fmaf(t1.w, w1[7], u1);
    u0 = fmaf(t2.x, w0[8], u0);  u1 = fmaf(t2.x, w1[8], u1);
    u0 = fmaf(t2.y, w0[9], u0);  u1 = fmaf(t2.y, w1[9], u1);
    u0 = fmaf(t2.z, w0[10], u0); u1 = fmaf(t2.z, w1[10], u1);
    u0 = fmaf(t2.w, w0[11], u0); u1 = fmaf(t2.w, w1[11], u1);
    u0 = fmaf(t3.x, w0[12], u0); u1 = fmaf(t3.x, w1[12], u1);
    u0 = fmaf(t3.y, w0[13], u0); u1 = fmaf(t3.y, w1[13], u1);
    u0 = fmaf(t3.z, w0[14], u0); u1 = fmaf(t3.z, w1[14], u1);
    u0 = fmaf(t3.w, w0[15], u0); u1 = fmaf(t3.w, w1[15], u1);
    a0 += fmaxf(u0, 0.f);
    a1 += fmaxf(u1, 0.f);
    cnt += 1.f;
  }
  if (cur >= 0) {
    atomicAdd(&esum[cur * 128 + lane], a0);
    atomicAdd(&esum[cur * 128 + 64 + lane], a1);
    if (lane == 0) atomicAdd(&ecnt[cur], cnt);
  }
}

// ---------------- final: graph_repr + edge_repr ----------------
__global__ __launch_bounds__(128) void final_kernel(const float* __restrict__ gsum,
                                                    const float* __restrict__ gcnt,
                                                    const float* __restrict__ esum,
                                                    const float* __restrict__ ecnt,
                                                    const float* __restrict__ We2,
                                                    const float* __restrict__ be2,
                                                    float* __restrict__ out) {
  __shared__ float row[128];
  int g = blockIdx.x, c = threadIdx.x;
  row[c] = esum[g * 128 + c];
  __syncthreads();
  float acc = 0.f;
#pragma unroll 4
  for (int k = 0; k < 128; ++k) acc = fmaf(row[k], We2[k * 128 + c], acc);
  float ce = ecnt[g];
  float er = (ce > 0.f) ? (acc / ce + be2[c]) : 0.f;
  float cn = gcnt[g];
  float gr = gsum[g * 128 + c] / fmaxf(cn, 1.f);
  out[g * 128 + c] = gr + er;
}

extern "C" void kernel_launch(void* const* d_in, const int* in_sizes, int n_in,
                              void* d_out, int out_size, void* d_ws, size_t ws_size,
                              hipStream_t stream) {
  const float* x    = (const float*)d_in[0];
  const int*   ei   = (const int*)d_in[1];
  const float* ea   = (const float*)d_in[2];
  const int*   bidx = (const int*)d_in[3];
  const float* Wg1  = (const float*)d_in[4];
  const float* bg1  = (const float*)d_in[5];
  const float* gm1  = (const float*)d_in[6];
  const float* bt1  = (const float*)d_in[7];
  const float* Wg2  = (const float*)d_in[8];
  const float* bg2  = (const float*)d_in[9];
  const float* gm2  = (const float*)d_in[10];
  const float* bt2  = (const float*)d_in[11];
  const float* We1  = (const float*)d_in[12];
  const float* be1  = (const float*)d_in[13];
  const float* We2  = (const float*)d_in[14];
  const float* be2  = (const float*)d_in[15];
  float* out = (float*)d_out;

  const int N = in_sizes[3];
  const int E = in_sizes[1] / 2;
  const int G = out_size / 128;
  const int* srcp = ei;
  const int* dstp = ei + E;

  char* w = (char*)d_ws;
  auto alloc = [&](size_t b) {
    char* p = w;
    w += (b + 15) & ~(size_t)15;
    return p;
  };
  float* bufA    = (float*)alloc((size_t)N * 128 * 4);
  float* bufB    = (float*)alloc((size_t)N * 128 * 4);
  int*   ssort   = (int*)alloc((size_t)E * 4);
  unsigned int* epk = (unsigned int*)alloc((size_t)E * 4);
  int*   rp      = (int*)alloc((size_t)(N + 1) * 4);
  int*   rp2     = (int*)alloc((size_t)(N + 1) * 4);
  int*   cursor  = (int*)alloc((size_t)N * 4);
  int*   cursor2 = (int*)alloc((size_t)N * 4);
  float* dinv    = (float*)alloc((size_t)N * 4);
  char* zbase = w;
  int*   deg  = (int*)alloc((size_t)N * 4);
  int*   deg2 = (int*)alloc((size_t)N * 4);
  float* bs1  = (float*)alloc(512);
  float* bq1  = (float*)alloc(512);
  float* bs2  = (float*)alloc(512);
  float* bq2  = (float*)alloc(512);
  float* gsum = (float*)alloc((size_t)G * 128 * 4);
  float* gcnt = (float*)alloc((size_t)G * 4);
  float* esum = (float*)alloc((size_t)G * 128 * 4);
  float* ecnt = (float*)alloc((size_t)G * 4);
  int*   part  = (int*)alloc(4096);
  int*   part2 = (int*)alloc(4096);
  size_t zbytes = (size_t)(w - zbase);
  float* sc1 = (float*)alloc(512);
  float* sh1 = (float*)alloc(512);
  float* sc2 = (float*)alloc(512);
  float* sh2 = (float*)alloc(512);

  hipMemsetAsync(zbase, 0, zbytes, stream);

  (void)hipFuncSetAttribute((const void*)gemm128_kernel,
                            hipFuncAttributeMaxDynamicSharedMemorySize, 73728);

  // histograms + CSR build (dst-CSR for SpMM, src-ordered edge list for edge path)
  pre_kernel<<<(E + 255) / 256, 256, 0, stream>>>(srcp, dstp, deg, deg2, E);
  dinv_kernel<<<(N + 255) / 256, 256, 0, stream>>>(deg, dinv, N);
  int nb = (N + 1023) / 1024;
  scan1_kernel<<<nb, 256, 0, stream>>>(deg, rp, part, N);
  scan2_kernel<<<1, 1, 0, stream>>>(part, rp, nb, N);
  scan3_kernel<<<(N + 255) / 256, 256, 0, stream>>>(rp, part, cursor, N);
  scan1_kernel<<<nb, 256, 0, stream>>>(deg2, rp2, part2, N);
  scan2_kernel<<<1, 1, 0, stream>>>(part2, rp2, nb, N);
  scan3_kernel<<<(N + 255) / 256, 256, 0, stream>>>(rp2, part2, cursor2, N);
  place_kernel<<<(E + 255) / 256, 256, 0, stream>>>(srcp, dstp, bidx, cursor, cursor2,
                                                    ssort, epk, E);

  // layer 1
  gemm128_kernel<<<512, 256, 73728, stream>>>(x, Wg1, bufA, N);
  spmm_kernel<<<2048, 256, 0, stream>>>(bufA, dinv, rp, ssort, bg1, bufB, bs1, bq1, N);
  bnfin_kernel<<<1, 128, 0, stream>>>(bs1, bq1, gm1, bt1, sc1, sh1, 1.0f / (float)N);
  bnapply_kernel<<<4096, 256, 0, stream>>>(bufB, sc1, sh1, bufA, N * 32);

  // layer 2
  gemm128_kernel<<<512, 256, 73728, stream>>>(bufA, Wg2, bufB, N);
  spmm_kernel<<<2048, 256, 0, stream>>>(bufB, dinv, rp, ssort, bg2, bufA, bs2, bq2, N);
  bnfin_kernel<<<1, 128, 0, stream>>>(bs2, bq2, gm2, bt2, sc2, sh2, 1.0f / (float)N);
  bnapply_kernel<<<4096, 256, 0, stream>>>(bufA, sc2, sh2, bufB, N * 32);

  // pooling + edge path + output
  int nwp = (2048 * 256) / 64;
  int chunkN = (N + nwp - 1) / nwp;
  pool_kernel<<<2048, 256, 0, stream>>>(bufB, bidx, gsum, gcnt, N, chunkN);
  int nwe = (2048 * 256) / 64;
  int chunkE = (E + nwe - 1) / nwe;
  edge2_kernel<<<2048, 256, 0, stream>>>(ea, epk, We1, be1, esum, ecnt, E, chunkE);
  final_kernel<<<G, 128, 0, stream>>>(gsum, gcnt, esum, ecnt, We2, be2, out);
}